// Round 1
// baseline (628.197 us; speedup 1.0000x reference)
//
#include <hip/hip_runtime.h>
#include <math.h>

#define NN 100000
#define NE 1600000
#define D 64
#define NEG_SLOPE 0.2f

// ---- order-preserving float<->uint encoding for atomicMax on floats ----
__device__ __forceinline__ unsigned enc_f32(float f) {
    unsigned u = __float_as_uint(f);
    return (u & 0x80000000u) ? ~u : (u | 0x80000000u);
}
__device__ __forceinline__ float dec_f32(unsigned k) {
    return (k & 0x80000000u) ? __uint_as_float(k ^ 0x80000000u)
                             : __uint_as_float(~k);
}

// K0: init out = feat + bias; emax = enc(-inf); denom = 0
__global__ __launch_bounds__(256) void k0_init(const float* __restrict__ feat,
                                               const float* __restrict__ bias,
                                               float* __restrict__ out,
                                               unsigned* __restrict__ emax,
                                               float* __restrict__ denom) {
    int idx = blockIdx.x * 256 + threadIdx.x;
    if (idx < NN * D) {
        out[idx] = feat[idx] + bias[idx & (D - 1)];
    }
    if (idx < NN) {
        emax[idx] = enc_f32(-INFINITY);
        denom[idx] = 0.0f;
    }
}

// K1: ft = feat @ W  (one wave per node), el/er wave-reduced dot products
__global__ __launch_bounds__(256) void k1_fc(const float* __restrict__ feat,
                                             const float* __restrict__ W,
                                             const float* __restrict__ attn_l,
                                             const float* __restrict__ attn_r,
                                             float* __restrict__ ft,
                                             float* __restrict__ el,
                                             float* __restrict__ er) {
    __shared__ float Ws[D * D];
    int tid = threadIdx.x;
    #pragma unroll
    for (int i = 0; i < D * D / 256; ++i) Ws[tid + i * 256] = W[tid + i * 256];
    __syncthreads();

    int lane = tid & 63;
    int wave = tid >> 6;
    int n = blockIdx.x * 4 + wave;
    if (n >= NN) return;

    float fv = feat[n * D + lane];
    float acc = 0.0f;
    #pragma unroll
    for (int k = 0; k < D; ++k) {
        float fk = __shfl(fv, k, 64);
        acc = fmaf(fk, Ws[k * D + lane], acc);
    }
    ft[n * D + lane] = acc;

    float pl = acc * attn_l[lane];
    float pr = acc * attn_r[lane];
    #pragma unroll
    for (int off = 32; off > 0; off >>= 1) {
        pl += __shfl_xor(pl, off, 64);
        pr += __shfl_xor(pr, off, 64);
    }
    if (lane == 0) { el[n] = pl; er[n] = pr; }
}

// K2: e = leaky_relu(el[src]+er[dst]); segment-max via atomicMax
__global__ __launch_bounds__(256) void k2_edge(const int* __restrict__ src,
                                               const int* __restrict__ dst,
                                               const float* __restrict__ el,
                                               const float* __restrict__ er,
                                               float* __restrict__ e_ws,
                                               unsigned* __restrict__ emax) {
    int i = blockIdx.x * 256 + threadIdx.x;
    if (i >= NE) return;
    int s = src[i], d = dst[i];
    float e = el[s] + er[d];
    e = e > 0.0f ? e : NEG_SLOPE * e;
    e_ws[i] = e;
    atomicMax(&emax[d], enc_f32(e));
}

// K3: e_exp = exp(e - emax[dst]); denom via atomicAdd
__global__ __launch_bounds__(256) void k3_exp(const int* __restrict__ dst,
                                              const unsigned* __restrict__ emax,
                                              float* __restrict__ e_ws,
                                              float* __restrict__ denom) {
    int i = blockIdx.x * 256 + threadIdx.x;
    if (i >= NE) return;
    int d = dst[i];
    float ex = __expf(e_ws[i] - dec_f32(emax[d]));
    e_ws[i] = ex;
    atomicAdd(&denom[d], ex);
}

// K4: out[dst][j] += ft[src][j] * (e_exp/denom[dst]); one wave per edge
__global__ __launch_bounds__(256) void k4_agg(const int* __restrict__ src,
                                              const int* __restrict__ dst,
                                              const float* __restrict__ ft,
                                              const float* __restrict__ e_ws,
                                              const float* __restrict__ denom,
                                              float* __restrict__ out) {
    int gid = blockIdx.x * 256 + threadIdx.x;
    int edge = gid >> 6;
    int lane = gid & 63;
    if (edge >= NE) return;
    int s = src[edge], d = dst[edge];
    float a = e_ws[edge] / denom[d];
    atomicAdd(&out[d * D + lane], ft[s * D + lane] * a);
}

extern "C" void kernel_launch(void* const* d_in, const int* in_sizes, int n_in,
                              void* d_out, int out_size, void* d_ws, size_t ws_size,
                              hipStream_t stream) {
    const float* feat   = (const float*)d_in[0];
    const float* W      = (const float*)d_in[1];
    const float* attn_l = (const float*)d_in[2];
    const float* attn_r = (const float*)d_in[3];
    const float* bias   = (const float*)d_in[4];
    const int*   src    = (const int*)d_in[5];
    const int*   dst    = (const int*)d_in[6];
    float* out = (float*)d_out;

    char* ws = (char*)d_ws;
    float*    ft    = (float*)(ws);                         // NN*D*4 = 25,600,000
    float*    el    = (float*)(ws + 25600000);              // NN*4
    float*    er    = (float*)(ws + 26000000);              // NN*4
    float*    e_ws  = (float*)(ws + 26400000);              // NE*4
    unsigned* emax  = (unsigned*)(ws + 32800000);           // NN*4
    float*    denom = (float*)(ws + 33200000);              // NN*4  (end 33,600,000)

    // K0: init out / emax / denom
    k0_init<<<(NN * D + 255) / 256, 256, 0, stream>>>(feat, bias, out, emax, denom);
    // K1: fc + attention halves
    k1_fc<<<(NN + 3) / 4, 256, 0, stream>>>(feat, W, attn_l, attn_r, ft, el, er);
    // K2: edge scores + segment max
    k2_edge<<<(NE + 255) / 256, 256, 0, stream>>>(src, dst, el, er, e_ws, emax);
    // K3: exp + segment sum
    k3_exp<<<(NE + 255) / 256, 256, 0, stream>>>(dst, emax, e_ws, denom);
    // K4: weighted aggregation
    k4_agg<<<(NE * 64 + 255) / 256, 256, 0, stream>>>(src, dst, ft, e_ws, denom, out);
}

// Round 2
// 428.387 us; speedup vs baseline: 1.4664x; 1.4664x over previous
//
#include <hip/hip_runtime.h>
#include <math.h>

#define NN 100000
#define NE 1600000
#define D 64
#define NEG_SLOPE 0.2f
#define NB_SCAN 98   // ceil(NN/1024)

// ---------------- CSR build ----------------

__global__ __launch_bounds__(256) void k_zero(unsigned* __restrict__ cnt) {
    int i = blockIdx.x * 256 + threadIdx.x;
    if (i < NN) cnt[i] = 0u;
}

__global__ __launch_bounds__(256) void k_hist(const int* __restrict__ dst,
                                              unsigned* __restrict__ cnt) {
    int i = blockIdx.x * 256 + threadIdx.x;
    if (i < NE) atomicAdd(&cnt[dst[i]], 1u);
}

// per-block exclusive scan of cnt -> row; block totals -> bsum
__global__ __launch_bounds__(1024) void scan_a(const unsigned* __restrict__ cnt,
                                               unsigned* __restrict__ row,
                                               unsigned* __restrict__ bsum) {
    __shared__ unsigned sh[1024];
    int t = threadIdx.x;
    int g = blockIdx.x * 1024 + t;
    unsigned v = (g < NN) ? cnt[g] : 0u;
    sh[t] = v; __syncthreads();
    for (int off = 1; off < 1024; off <<= 1) {
        unsigned u = (t >= off) ? sh[t - off] : 0u;
        __syncthreads();
        sh[t] += u; __syncthreads();
    }
    unsigned ex = (t == 0) ? 0u : sh[t - 1];
    if (g < NN) row[g] = ex;
    if (t == 1023) bsum[blockIdx.x] = sh[1023];
}

// exclusive scan of the 98 block sums, in place (single block of 128)
__global__ __launch_bounds__(128) void scan_b(unsigned* __restrict__ bsum) {
    __shared__ unsigned sh[128];
    int t = threadIdx.x;
    unsigned v = (t < NB_SCAN) ? bsum[t] : 0u;
    sh[t] = v; __syncthreads();
    for (int off = 1; off < 128; off <<= 1) {
        unsigned u = (t >= off) ? sh[t - off] : 0u;
        __syncthreads();
        sh[t] += u; __syncthreads();
    }
    if (t < NB_SCAN) bsum[t] = t ? sh[t - 1] : 0u;
}

// add block offsets; init cursor = row (cursor aliases cnt)
__global__ __launch_bounds__(1024) void scan_c(unsigned* __restrict__ row,
                                               const unsigned* __restrict__ bsum,
                                               unsigned* __restrict__ cursor) {
    int g = blockIdx.x * 1024 + threadIdx.x;
    if (g < NN) {
        unsigned r = row[g] + bsum[blockIdx.x];
        row[g] = r;
        cursor[g] = r;
    }
}

// place src ids into dst-sorted order; after this, cursor[d] == row end of d
__global__ __launch_bounds__(256) void k_scatter(const int* __restrict__ src,
                                                 const int* __restrict__ dst,
                                                 unsigned* __restrict__ cursor,
                                                 int* __restrict__ perm_src) {
    int i = blockIdx.x * 256 + threadIdx.x;
    if (i >= NE) return;
    unsigned pos = atomicAdd(&cursor[dst[i]], 1u);
    perm_src[pos] = src[i];
}

// ---------------- dense phase ----------------

// ft = feat @ W (one wave per node); el/er via wave dot-reduce
__global__ __launch_bounds__(256) void k1_fc(const float* __restrict__ feat,
                                             const float* __restrict__ W,
                                             const float* __restrict__ attn_l,
                                             const float* __restrict__ attn_r,
                                             float* __restrict__ ft,
                                             float* __restrict__ el,
                                             float* __restrict__ er) {
    __shared__ float Ws[D * D];
    int tid = threadIdx.x;
    #pragma unroll
    for (int i = 0; i < D * D / 256; ++i) Ws[tid + i * 256] = W[tid + i * 256];
    __syncthreads();

    int lane = tid & 63;
    int wave = tid >> 6;
    int n = blockIdx.x * 4 + wave;
    if (n >= NN) return;

    float fv = feat[n * D + lane];
    float acc = 0.0f;
    #pragma unroll
    for (int k = 0; k < D; ++k) {
        float fk = __shfl(fv, k, 64);
        acc = fmaf(fk, Ws[k * D + lane], acc);
    }
    ft[n * D + lane] = acc;

    float pl = acc * attn_l[lane];
    float pr = acc * attn_r[lane];
    #pragma unroll
    for (int off = 32; off > 0; off >>= 1) {
        pl += __shfl_xor(pl, off, 64);
        pr += __shfl_xor(pr, off, 64);
    }
    if (lane == 0) { el[n] = pl; er[n] = pr; }
}

// fused edge-softmax + weighted aggregation + residual + bias.
// one wave per destination node; single coalesced 256B write per node.
__global__ __launch_bounds__(256) void k_agg(const unsigned* __restrict__ row,
                                             const unsigned* __restrict__ rend,
                                             const int* __restrict__ perm_src,
                                             const float* __restrict__ el,
                                             const float* __restrict__ er,
                                             const float* __restrict__ ft,
                                             const float* __restrict__ feat,
                                             const float* __restrict__ bias,
                                             float* __restrict__ out) {
    int gid = blockIdx.x * 256 + threadIdx.x;
    int d = gid >> 6;
    int lane = gid & 63;
    if (d >= NN) return;

    unsigned beg = row[d], end = rend[d];
    int deg = (int)(end - beg);
    float er_d = er[d];
    float acc = 0.0f;
    float s = 0.0f;

    if (deg <= 64) {
        // stash edge data in registers
        int sid = 0;
        float e = -INFINITY;
        if (lane < deg) {
            sid = perm_src[beg + lane];
            float v = el[sid] + er_d;
            e = v > 0.0f ? v : NEG_SLOPE * v;
        }
        float m = e;
        #pragma unroll
        for (int off = 32; off > 0; off >>= 1) m = fmaxf(m, __shfl_xor(m, off, 64));
        float ex = (lane < deg) ? __expf(e - m) : 0.0f;
        s = ex;
        #pragma unroll
        for (int off = 32; off > 0; off >>= 1) s += __shfl_xor(s, off, 64);

        for (int j = 0; j < deg; ++j) {
            int sj = __shfl(sid, j, 64);
            float aj = __shfl(ex, j, 64);
            acc = fmaf(ft[sj * D + lane], aj, acc);
        }
    } else {
        // generic fallback (deg > 64): streaming max, then sum, then recompute
        float m = -INFINITY;
        for (unsigned base = beg; base < end; base += 64) {
            unsigned i = base + lane;
            float e = -INFINITY;
            if (i < end) {
                int sid = perm_src[i];
                float v = el[sid] + er_d;
                e = v > 0.0f ? v : NEG_SLOPE * v;
            }
            #pragma unroll
            for (int off = 32; off > 0; off >>= 1) e = fmaxf(e, __shfl_xor(e, off, 64));
            m = fmaxf(m, e);
        }
        for (unsigned base = beg; base < end; base += 64) {
            unsigned i = base + lane;
            float ex = 0.0f;
            if (i < end) {
                int sid = perm_src[i];
                float v = el[sid] + er_d;
                v = v > 0.0f ? v : NEG_SLOPE * v;
                ex = __expf(v - m);
            }
            #pragma unroll
            for (int off = 32; off > 0; off >>= 1) ex += __shfl_xor(ex, off, 64);
            s += ex;
        }
        for (unsigned j = beg; j < end; ++j) {
            int sj = perm_src[j];
            float v = el[sj] + er_d;
            v = v > 0.0f ? v : NEG_SLOPE * v;
            acc = fmaf(ft[sj * D + lane], __expf(v - m), acc);
        }
    }

    if (deg > 0) acc /= s;
    out[d * D + lane] = acc + feat[d * D + lane] + bias[lane];
}

extern "C" void kernel_launch(void* const* d_in, const int* in_sizes, int n_in,
                              void* d_out, int out_size, void* d_ws, size_t ws_size,
                              hipStream_t stream) {
    const float* feat   = (const float*)d_in[0];
    const float* W      = (const float*)d_in[1];
    const float* attn_l = (const float*)d_in[2];
    const float* attn_r = (const float*)d_in[3];
    const float* bias   = (const float*)d_in[4];
    const int*   src    = (const int*)d_in[5];
    const int*   dst    = (const int*)d_in[6];
    float* out = (float*)d_out;

    char* ws = (char*)d_ws;
    float*    ft     = (float*)(ws);                 // 25,600,000 B
    float*    el     = (float*)(ws + 25600000);      // 400,000 B (bsum aliases head)
    float*    er     = (float*)(ws + 26000000);      // 400,000 B
    unsigned* cntcur = (unsigned*)(ws + 26400000);   // 400,000 B (cnt, then cursor)
    unsigned* rowp   = (unsigned*)(ws + 26800000);   // 400,000 B
    int*      perm   = (int*)(ws + 27200000);        // 6,400,000 B  (end 33,600,000)
    unsigned* bsum   = (unsigned*)el;                // dead until k1_fc runs

    // CSR build
    k_zero<<<(NN + 255) / 256, 256, 0, stream>>>(cntcur);
    k_hist<<<(NE + 255) / 256, 256, 0, stream>>>(dst, cntcur);
    scan_a<<<NB_SCAN, 1024, 0, stream>>>(cntcur, rowp, bsum);
    scan_b<<<1, 128, 0, stream>>>(bsum);
    scan_c<<<NB_SCAN, 1024, 0, stream>>>(rowp, bsum, cntcur);
    k_scatter<<<(NE + 255) / 256, 256, 0, stream>>>(src, dst, cntcur, perm);

    // dense phase
    k1_fc<<<(NN + 3) / 4, 256, 0, stream>>>(feat, W, attn_l, attn_r, ft, el, er);
    k_agg<<<(NN * 64 + 255) / 256, 256, 0, stream>>>(rowp, cntcur, perm, el, er,
                                                     ft, feat, bias, out);
}

// Round 3
// 296.436 us; speedup vs baseline: 2.1192x; 1.4451x over previous
//
#include <hip/hip_runtime.h>
#include <math.h>

#define NN 100000
#define NE 1600000
#define D 64
#define NEG_SLOPE 0.2f
#define BSH 8
#define BMASK 255
#define NBKT 391          // ceil(NN / 256)
#define NB1 196           // streaming blocks for hist/bin
#define CHUNK 8192        // edges per streaming block

// ---------------- bucket histogram (LDS pre-aggregated) ----------------
__global__ __launch_bounds__(256) void k_bhist(const int* __restrict__ dst,
                                               unsigned* __restrict__ bcnt) {
    __shared__ unsigned lh[NBKT];
    int t = threadIdx.x;
    unsigned b0 = blockIdx.x * CHUNK;
    unsigned b1 = min(b0 + CHUNK, (unsigned)NE);
    for (int b = t; b < NBKT; b += 256) lh[b] = 0u;
    __syncthreads();
    for (unsigned i = b0 + t; i < b1; i += 256)
        atomicAdd(&lh[((unsigned)dst[i]) >> BSH], 1u);
    __syncthreads();
    for (int b = t; b < NBKT; b += 256)
        if (lh[b]) atomicAdd(&bcnt[b], lh[b]);
}

// scan 391 bucket counts -> bases + cursors (single block)
__global__ __launch_bounds__(512) void k_bscan(const unsigned* __restrict__ bcnt,
                                               unsigned* __restrict__ bkt_base,
                                               unsigned* __restrict__ bkt_cur) {
    __shared__ unsigned sh[512];
    int t = threadIdx.x;
    sh[t] = (t < NBKT) ? bcnt[t] : 0u;
    __syncthreads();
    for (int off = 1; off < 512; off <<= 1) {
        unsigned u = (t >= off) ? sh[t - off] : 0u;
        __syncthreads();
        sh[t] += u;
        __syncthreads();
    }
    if (t < NBKT) {
        unsigned ex = t ? sh[t - 1] : 0u;
        bkt_base[t] = ex;
        bkt_cur[t] = ex;
    }
}

// bin edges into bucket-contiguous runs: packed word = (src<<8)|dst_local
__global__ __launch_bounds__(256) void k_bin(const int* __restrict__ src,
                                             const int* __restrict__ dst,
                                             unsigned* __restrict__ bkt_cur,
                                             unsigned* __restrict__ binned) {
    __shared__ unsigned lh[NBKT];
    int t = threadIdx.x;
    unsigned b0 = blockIdx.x * CHUNK;
    unsigned b1 = min(b0 + CHUNK, (unsigned)NE);
    for (int b = t; b < NBKT; b += 256) lh[b] = 0u;
    __syncthreads();
    for (unsigned i = b0 + t; i < b1; i += 256)
        atomicAdd(&lh[((unsigned)dst[i]) >> BSH], 1u);
    __syncthreads();
    for (int b = t; b < NBKT; b += 256) {
        unsigned c = lh[b];
        lh[b] = c ? atomicAdd(&bkt_cur[b], c) : 0u;   // global run base for this block
    }
    __syncthreads();
    for (unsigned i = b0 + t; i < b1; i += 256) {
        unsigned dv = (unsigned)dst[i];
        unsigned bk = dv >> BSH;
        unsigned pos = atomicAdd(&lh[bk], 1u);
        binned[pos] = (((unsigned)src[i]) << BSH) | (dv & BMASK);
    }
}

// per-bucket counting sort; writes global row offsets + dst-sorted src ids
__global__ __launch_bounds__(256) void k_bsort(const unsigned* __restrict__ bkt_base,
                                               const unsigned* __restrict__ binned,
                                               int* __restrict__ perm,
                                               unsigned* __restrict__ rowp) {
    __shared__ unsigned lh[256];
    __shared__ unsigned cur[256];
    int t = threadIdx.x;
    int b = blockIdx.x;
    unsigned beg = bkt_base[b];
    unsigned end = (b == NBKT - 1) ? (unsigned)NE : bkt_base[b + 1];
    lh[t] = 0u;
    __syncthreads();
    for (unsigned i = beg + t; i < end; i += 256)
        atomicAdd(&lh[binned[i] & BMASK], 1u);
    __syncthreads();
    for (int off = 1; off < 256; off <<= 1) {      // inclusive scan of lh
        unsigned u = (t >= off) ? lh[t - off] : 0u;
        __syncthreads();
        lh[t] += u;
        __syncthreads();
    }
    unsigned start = (t == 0) ? 0u : lh[t - 1];
    unsigned node = ((unsigned)b << BSH) + (unsigned)t;
    if (node <= NN) rowp[node] = beg + start;      // row[NN]=NE from last bucket
    cur[t] = start;
    __syncthreads();
    for (unsigned i = beg + t; i < end; i += 256) {
        unsigned w = binned[i];                     // L2-hot second read
        unsigned pos = atomicAdd(&cur[w & BMASK], 1u);
        perm[beg + pos] = (int)(w >> BSH);
    }
}

// ---------------- dense phase ----------------

// ft = feat @ W (one wave per node); el/er via wave dot-reduce
__global__ __launch_bounds__(256) void k1_fc(const float* __restrict__ feat,
                                             const float* __restrict__ W,
                                             const float* __restrict__ attn_l,
                                             const float* __restrict__ attn_r,
                                             float* __restrict__ ft,
                                             float* __restrict__ el,
                                             float* __restrict__ er) {
    __shared__ float Ws[D * D];
    int tid = threadIdx.x;
    #pragma unroll
    for (int i = 0; i < D * D / 256; ++i) Ws[tid + i * 256] = W[tid + i * 256];
    __syncthreads();

    int lane = tid & 63;
    int wave = tid >> 6;
    int n = blockIdx.x * 4 + wave;
    if (n >= NN) return;

    float fv = feat[n * D + lane];
    float acc = 0.0f;
    #pragma unroll
    for (int k = 0; k < D; ++k) {
        float fk = __shfl(fv, k, 64);
        acc = fmaf(fk, Ws[k * D + lane], acc);
    }
    ft[n * D + lane] = acc;

    float pl = acc * attn_l[lane];
    float pr = acc * attn_r[lane];
    #pragma unroll
    for (int off = 32; off > 0; off >>= 1) {
        pl += __shfl_xor(pl, off, 64);
        pr += __shfl_xor(pr, off, 64);
    }
    if (lane == 0) { el[n] = pl; er[n] = pr; }
}

// fused edge-softmax + weighted aggregation + residual + bias
// one wave per destination node; single coalesced 256B write per node
__global__ __launch_bounds__(256) void k_agg(const unsigned* __restrict__ row,
                                             const int* __restrict__ perm_src,
                                             const float* __restrict__ el,
                                             const float* __restrict__ er,
                                             const float* __restrict__ ft,
                                             const float* __restrict__ feat,
                                             const float* __restrict__ bias,
                                             float* __restrict__ out) {
    int gid = blockIdx.x * 256 + threadIdx.x;
    int d = gid >> 6;
    int lane = gid & 63;
    if (d >= NN) return;

    unsigned beg = row[d], end = row[d + 1];
    int deg = (int)(end - beg);
    float er_d = er[d];
    float acc = 0.0f;
    float s = 0.0f;

    if (deg <= 64) {
        int sid = 0;
        float e = -INFINITY;
        if (lane < deg) {
            sid = perm_src[beg + lane];
            float v = el[sid] + er_d;
            e = v > 0.0f ? v : NEG_SLOPE * v;
        }
        float m = e;
        #pragma unroll
        for (int off = 32; off > 0; off >>= 1) m = fmaxf(m, __shfl_xor(m, off, 64));
        float ex = (lane < deg) ? __expf(e - m) : 0.0f;
        s = ex;
        #pragma unroll
        for (int off = 32; off > 0; off >>= 1) s += __shfl_xor(s, off, 64);

        for (int j = 0; j < deg; ++j) {
            int sj = __shfl(sid, j, 64);
            float aj = __shfl(ex, j, 64);
            acc = fmaf(ft[sj * D + lane], aj, acc);
        }
    } else {
        float m = -INFINITY;
        for (unsigned base = beg; base < end; base += 64) {
            unsigned i = base + lane;
            float e = -INFINITY;
            if (i < end) {
                int sid = perm_src[i];
                float v = el[sid] + er_d;
                e = v > 0.0f ? v : NEG_SLOPE * v;
            }
            #pragma unroll
            for (int off = 32; off > 0; off >>= 1) e = fmaxf(e, __shfl_xor(e, off, 64));
            m = fmaxf(m, e);
        }
        for (unsigned base = beg; base < end; base += 64) {
            unsigned i = base + lane;
            float ex = 0.0f;
            if (i < end) {
                int sid = perm_src[i];
                float v = el[sid] + er_d;
                v = v > 0.0f ? v : NEG_SLOPE * v;
                ex = __expf(v - m);
            }
            #pragma unroll
            for (int off = 32; off > 0; off >>= 1) ex += __shfl_xor(ex, off, 64);
            s += ex;
        }
        for (unsigned j = beg; j < end; ++j) {
            int sj = perm_src[j];
            float v = el[sj] + er_d;
            v = v > 0.0f ? v : NEG_SLOPE * v;
            acc = fmaf(ft[sj * D + lane], __expf(v - m), acc);
        }
    }

    if (deg > 0) acc /= s;
    out[d * D + lane] = acc + feat[d * D + lane] + bias[lane];
}

extern "C" void kernel_launch(void* const* d_in, const int* in_sizes, int n_in,
                              void* d_out, int out_size, void* d_ws, size_t ws_size,
                              hipStream_t stream) {
    const float* feat   = (const float*)d_in[0];
    const float* W      = (const float*)d_in[1];
    const float* attn_l = (const float*)d_in[2];
    const float* attn_r = (const float*)d_in[3];
    const float* bias   = (const float*)d_in[4];
    const int*   src    = (const int*)d_in[5];
    const int*   dst    = (const int*)d_in[6];
    float* out = (float*)d_out;

    char* ws = (char*)d_ws;
    float*    ft     = (float*)(ws);                 // 25,600,000 B
    unsigned* binned = (unsigned*)(ws);              // aliases ft[0:6.4MB]; dead before k1_fc
    float*    el     = (float*)(ws + 25600000);      // 400,000 B
    float*    er     = (float*)(ws + 26000000);      // 400,000 B
    int*      perm   = (int*)(ws + 26400000);        // 6,400,000 B
    unsigned* rowp   = (unsigned*)(ws + 32800000);   // 400,004 B  (NN+1)
    unsigned* bcnt   = (unsigned*)(ws + 33200004);   // 1,564 B
    unsigned* bbase  = (unsigned*)(ws + 33201568);   // 1,564 B
    unsigned* bcur   = (unsigned*)(ws + 33203132);   // 1,564 B  (end 33,204,696)

    hipMemsetAsync(bcnt, 0, NBKT * sizeof(unsigned), stream);
    k_bhist<<<NB1, 256, 0, stream>>>(dst, bcnt);
    k_bscan<<<1, 512, 0, stream>>>(bcnt, bbase, bcur);
    k_bin<<<NB1, 256, 0, stream>>>(src, dst, bcur, binned);
    k_bsort<<<NBKT, 256, 0, stream>>>(bbase, binned, perm, rowp);

    k1_fc<<<(NN + 3) / 4, 256, 0, stream>>>(feat, W, attn_l, attn_r, ft, el, er);
    k_agg<<<(NN * 64 + 255) / 256, 256, 0, stream>>>(rowp, perm, el, er,
                                                     ft, feat, bias, out);
}

// Round 4
// 219.506 us; speedup vs baseline: 2.8619x; 1.3505x over previous
//
#include <hip/hip_runtime.h>
#include <math.h>

#define NN 100000
#define NE 1600000
#define D 64
#define NEG_SLOPE 0.2f
#define BSH 8
#define BMASK 255
#define NBKT 391          // ceil(NN / 256)
#define NB1 196           // streaming blocks for hist/bin
#define CHUNK 8192        // edges per streaming block

// ---------------- DPP wave64 sum (VALU pipe, no LDS) ----------------
template<int CTRL>
__device__ __forceinline__ float dpp_add(float x) {
    int y = __builtin_amdgcn_update_dpp(0, __float_as_int(x), CTRL, 0xf, 0xf, true);
    return x + __int_as_float(y);
}
// full 64-lane sum, valid in lane 63
__device__ __forceinline__ float wave_sum63(float x) {
    x = dpp_add<0x111>(x);   // row_shr:1
    x = dpp_add<0x112>(x);   // row_shr:2
    x = dpp_add<0x114>(x);   // row_shr:4
    x = dpp_add<0x118>(x);   // row_shr:8
    x = dpp_add<0x142>(x);   // row_bcast:15
    x = dpp_add<0x143>(x);   // row_bcast:31
    return x;
}

// ---------------- bucket histogram (LDS pre-aggregated) ----------------
__global__ __launch_bounds__(256) void k_bhist(const int* __restrict__ dst,
                                               unsigned* __restrict__ bcnt) {
    __shared__ unsigned lh[NBKT];
    int t = threadIdx.x;
    unsigned b0 = blockIdx.x * CHUNK;
    unsigned b1 = min(b0 + CHUNK, (unsigned)NE);
    for (int b = t; b < NBKT; b += 256) lh[b] = 0u;
    __syncthreads();
    for (unsigned i = b0 + t; i < b1; i += 256)
        atomicAdd(&lh[((unsigned)dst[i]) >> BSH], 1u);
    __syncthreads();
    for (int b = t; b < NBKT; b += 256)
        if (lh[b]) atomicAdd(&bcnt[b], lh[b]);
}

// scan 391 bucket counts -> bases + cursors (single block)
__global__ __launch_bounds__(512) void k_bscan(const unsigned* __restrict__ bcnt,
                                               unsigned* __restrict__ bkt_base,
                                               unsigned* __restrict__ bkt_cur) {
    __shared__ unsigned sh[512];
    int t = threadIdx.x;
    sh[t] = (t < NBKT) ? bcnt[t] : 0u;
    __syncthreads();
    for (int off = 1; off < 512; off <<= 1) {
        unsigned u = (t >= off) ? sh[t - off] : 0u;
        __syncthreads();
        sh[t] += u;
        __syncthreads();
    }
    if (t < NBKT) {
        unsigned ex = t ? sh[t - 1] : 0u;
        bkt_base[t] = ex;
        bkt_cur[t] = ex;
    }
}

// bin edges into bucket-contiguous runs: packed word = (src<<8)|dst_local
__global__ __launch_bounds__(256) void k_bin(const int* __restrict__ src,
                                             const int* __restrict__ dst,
                                             unsigned* __restrict__ bkt_cur,
                                             unsigned* __restrict__ binned) {
    __shared__ unsigned lh[NBKT];
    int t = threadIdx.x;
    unsigned b0 = blockIdx.x * CHUNK;
    unsigned b1 = min(b0 + CHUNK, (unsigned)NE);
    for (int b = t; b < NBKT; b += 256) lh[b] = 0u;
    __syncthreads();
    for (unsigned i = b0 + t; i < b1; i += 256)
        atomicAdd(&lh[((unsigned)dst[i]) >> BSH], 1u);
    __syncthreads();
    for (int b = t; b < NBKT; b += 256) {
        unsigned c = lh[b];
        lh[b] = c ? atomicAdd(&bkt_cur[b], c) : 0u;   // global run base for this block
    }
    __syncthreads();
    for (unsigned i = b0 + t; i < b1; i += 256) {
        unsigned dv = (unsigned)dst[i];
        unsigned bk = dv >> BSH;
        unsigned pos = atomicAdd(&lh[bk], 1u);
        binned[pos] = (((unsigned)src[i]) << BSH) | (dv & BMASK);
    }
}

// per-bucket counting sort; writes global row offsets + dst-sorted src ids
__global__ __launch_bounds__(256) void k_bsort(const unsigned* __restrict__ bkt_base,
                                               const unsigned* __restrict__ binned,
                                               int* __restrict__ perm,
                                               unsigned* __restrict__ rowp) {
    __shared__ unsigned lh[256];
    __shared__ unsigned cur[256];
    int t = threadIdx.x;
    int b = blockIdx.x;
    unsigned beg = bkt_base[b];
    unsigned end = (b == NBKT - 1) ? (unsigned)NE : bkt_base[b + 1];
    lh[t] = 0u;
    __syncthreads();
    for (unsigned i = beg + t; i < end; i += 256)
        atomicAdd(&lh[binned[i] & BMASK], 1u);
    __syncthreads();
    for (int off = 1; off < 256; off <<= 1) {      // inclusive scan of lh
        unsigned u = (t >= off) ? lh[t - off] : 0u;
        __syncthreads();
        lh[t] += u;
        __syncthreads();
    }
    unsigned start = (t == 0) ? 0u : lh[t - 1];
    unsigned node = ((unsigned)b << BSH) + (unsigned)t;
    if (node <= NN) rowp[node] = beg + start;      // row[NN]=NE from last bucket
    cur[t] = start;
    __syncthreads();
    for (unsigned i = beg + t; i < end; i += 256) {
        unsigned w = binned[i];                     // L2-hot second read
        unsigned pos = atomicAdd(&cur[w & BMASK], 1u);
        perm[beg + pos] = (int)(w >> BSH);
    }
}

// ---------------- dense phase ----------------

// ft = feat @ W. W column `lane` lives in 64 VGPRs; feat row arrives via
// wave-uniform (scalar) loads; zero LDS/DS ops in the k-loop.
// el/er via DPP wave reduce (VALU pipe). 16 nodes per wave.
__global__ __launch_bounds__(256) void k1_fc(const float* __restrict__ feat,
                                             const float* __restrict__ W,
                                             const float* __restrict__ attn_l,
                                             const float* __restrict__ attn_r,
                                             float* __restrict__ ft,
                                             float* __restrict__ el,
                                             float* __restrict__ er) {
    int lane = threadIdx.x & 63;
    int wv = __builtin_amdgcn_readfirstlane(threadIdx.x >> 6);

    float wreg[64];
    #pragma unroll
    for (int k = 0; k < 64; ++k) wreg[k] = W[k * D + lane];
    float al = attn_l[lane];
    float ar = attn_r[lane];

    int n0 = blockIdx.x * 64 + wv * 16;
    #pragma unroll 1
    for (int r = 0; r < 16; ++r) {
        int n = n0 + r;
        if (n >= NN) return;
        const float* p = feat + (size_t)n * D;   // wave-uniform address
        float a0 = 0.f, a1 = 0.f, a2 = 0.f, a3 = 0.f;
        #pragma unroll
        for (int kk = 0; kk < 4; ++kk) {
            float f[16];
            #pragma unroll
            for (int k = 0; k < 16; ++k) f[k] = p[kk * 16 + k];
            #pragma unroll
            for (int k = 0; k < 16; ++k) {
                int ki = kk * 16 + k;
                if ((k & 3) == 0)      a0 = fmaf(f[k], wreg[ki], a0);
                else if ((k & 3) == 1) a1 = fmaf(f[k], wreg[ki], a1);
                else if ((k & 3) == 2) a2 = fmaf(f[k], wreg[ki], a2);
                else                   a3 = fmaf(f[k], wreg[ki], a3);
            }
        }
        float a = (a0 + a1) + (a2 + a3);
        ft[(size_t)n * D + lane] = a;
        float pl = wave_sum63(a * al);
        float pr = wave_sum63(a * ar);
        if (lane == 63) { el[n] = pl; er[n] = pr; }
    }
}

// fused edge-softmax + weighted aggregation + residual + bias
// one wave per destination node; single coalesced 256B write per node
__global__ __launch_bounds__(256) void k_agg(const unsigned* __restrict__ row,
                                             const int* __restrict__ perm_src,
                                             const float* __restrict__ el,
                                             const float* __restrict__ er,
                                             const float* __restrict__ ft,
                                             const float* __restrict__ feat,
                                             const float* __restrict__ bias,
                                             float* __restrict__ out) {
    int gid = blockIdx.x * 256 + threadIdx.x;
    int d = gid >> 6;
    int lane = gid & 63;
    if (d >= NN) return;

    unsigned beg = row[d], end = row[d + 1];
    int deg = (int)(end - beg);
    float er_d = er[d];
    float acc = 0.0f;
    float s = 0.0f;

    if (deg <= 64) {
        int sid = 0;
        float e = -INFINITY;
        if (lane < deg) {
            sid = perm_src[beg + lane];
            float v = el[sid] + er_d;
            e = v > 0.0f ? v : NEG_SLOPE * v;
        }
        float m = e;
        #pragma unroll
        for (int off = 32; off > 0; off >>= 1) m = fmaxf(m, __shfl_xor(m, off, 64));
        float ex = (lane < deg) ? __expf(e - m) : 0.0f;
        s = ex;
        #pragma unroll
        for (int off = 32; off > 0; off >>= 1) s += __shfl_xor(s, off, 64);

        for (int j = 0; j < deg; ++j) {
            int sj = __shfl(sid, j, 64);
            float aj = __shfl(ex, j, 64);
            acc = fmaf(ft[sj * D + lane], aj, acc);
        }
    } else {
        float m = -INFINITY;
        for (unsigned base = beg; base < end; base += 64) {
            unsigned i = base + lane;
            float e = -INFINITY;
            if (i < end) {
                int sid = perm_src[i];
                float v = el[sid] + er_d;
                e = v > 0.0f ? v : NEG_SLOPE * v;
            }
            #pragma unroll
            for (int off = 32; off > 0; off >>= 1) e = fmaxf(e, __shfl_xor(e, off, 64));
            m = fmaxf(m, e);
        }
        for (unsigned base = beg; base < end; base += 64) {
            unsigned i = base + lane;
            float ex = 0.0f;
            if (i < end) {
                int sid = perm_src[i];
                float v = el[sid] + er_d;
                v = v > 0.0f ? v : NEG_SLOPE * v;
                ex = __expf(v - m);
            }
            #pragma unroll
            for (int off = 32; off > 0; off >>= 1) ex += __shfl_xor(ex, off, 64);
            s += ex;
        }
        for (unsigned j = beg; j < end; ++j) {
            int sj = perm_src[j];
            float v = el[sj] + er_d;
            v = v > 0.0f ? v : NEG_SLOPE * v;
            acc = fmaf(ft[sj * D + lane], __expf(v - m), acc);
        }
    }

    if (deg > 0) acc /= s;
    out[d * D + lane] = acc + feat[d * D + lane] + bias[lane];
}

extern "C" void kernel_launch(void* const* d_in, const int* in_sizes, int n_in,
                              void* d_out, int out_size, void* d_ws, size_t ws_size,
                              hipStream_t stream) {
    const float* feat   = (const float*)d_in[0];
    const float* W      = (const float*)d_in[1];
    const float* attn_l = (const float*)d_in[2];
    const float* attn_r = (const float*)d_in[3];
    const float* bias   = (const float*)d_in[4];
    const int*   src    = (const int*)d_in[5];
    const int*   dst    = (const int*)d_in[6];
    float* out = (float*)d_out;

    char* ws = (char*)d_ws;
    float*    ft     = (float*)(ws);                 // 25,600,000 B
    unsigned* binned = (unsigned*)(ws);              // aliases ft[0:6.4MB]; dead before k1_fc
    float*    el     = (float*)(ws + 25600000);      // 400,000 B
    float*    er     = (float*)(ws + 26000000);      // 400,000 B
    int*      perm   = (int*)(ws + 26400000);        // 6,400,000 B
    unsigned* rowp   = (unsigned*)(ws + 32800000);   // 400,004 B  (NN+1)
    unsigned* bcnt   = (unsigned*)(ws + 33200004);   // 1,564 B
    unsigned* bbase  = (unsigned*)(ws + 33201568);   // 1,564 B
    unsigned* bcur   = (unsigned*)(ws + 33203132);   // 1,564 B  (end 33,204,696)

    hipMemsetAsync(bcnt, 0, NBKT * sizeof(unsigned), stream);
    k_bhist<<<NB1, 256, 0, stream>>>(dst, bcnt);
    k_bscan<<<1, 512, 0, stream>>>(bcnt, bbase, bcur);
    k_bin<<<NB1, 256, 0, stream>>>(src, dst, bcur, binned);
    k_bsort<<<NBKT, 256, 0, stream>>>(bbase, binned, perm, rowp);

    k1_fc<<<(NN + 63) / 64, 256, 0, stream>>>(feat, W, attn_l, attn_r, ft, el, er);
    k_agg<<<(NN * 64 + 255) / 256, 256, 0, stream>>>(rowp, perm, el, er,
                                                     ft, feat, bias, out);
}

// Round 5
// 174.237 us; speedup vs baseline: 3.6054x; 1.2598x over previous
//
#include <hip/hip_runtime.h>
#include <math.h>

#define NN 100000
#define NE 1600000
#define D 64
#define NEG_SLOPE 0.2f
#define BSH 8
#define BMASK 255
#define NBKT 391          // ceil(NN / 256)
#define NB1 196           // streaming blocks for hist/bin
#define CHUNK 8192        // edges per streaming block

// ---------------- DPP wave64 sum (VALU pipe, no LDS) ----------------
template<int CTRL>
__device__ __forceinline__ float dpp_add(float x) {
    int y = __builtin_amdgcn_update_dpp(0, __float_as_int(x), CTRL, 0xf, 0xf, true);
    return x + __int_as_float(y);
}
// full 64-lane sum, valid in lane 63
__device__ __forceinline__ float wave_sum63(float x) {
    x = dpp_add<0x111>(x);   // row_shr:1
    x = dpp_add<0x112>(x);   // row_shr:2
    x = dpp_add<0x114>(x);   // row_shr:4
    x = dpp_add<0x118>(x);   // row_shr:8
    x = dpp_add<0x142>(x);   // row_bcast:15
    x = dpp_add<0x143>(x);   // row_bcast:31
    return x;
}

__device__ __forceinline__ float rdlane_f(float v, int l) {
    return __int_as_float(__builtin_amdgcn_readlane(__float_as_int(v), l));
}

// ---------------- bucket histogram (LDS pre-aggregated) ----------------
__global__ __launch_bounds__(256) void k_bhist(const int* __restrict__ dst,
                                               unsigned* __restrict__ bcnt) {
    __shared__ unsigned lh[NBKT];
    int t = threadIdx.x;
    unsigned b0 = blockIdx.x * CHUNK;
    unsigned b1 = min(b0 + CHUNK, (unsigned)NE);
    for (int b = t; b < NBKT; b += 256) lh[b] = 0u;
    __syncthreads();
    for (unsigned i = b0 + t; i < b1; i += 256)
        atomicAdd(&lh[((unsigned)dst[i]) >> BSH], 1u);
    __syncthreads();
    for (int b = t; b < NBKT; b += 256)
        if (lh[b]) atomicAdd(&bcnt[b], lh[b]);
}

// scan 391 bucket counts -> bases + cursors (single block)
__global__ __launch_bounds__(512) void k_bscan(const unsigned* __restrict__ bcnt,
                                               unsigned* __restrict__ bkt_base,
                                               unsigned* __restrict__ bkt_cur) {
    __shared__ unsigned sh[512];
    int t = threadIdx.x;
    sh[t] = (t < NBKT) ? bcnt[t] : 0u;
    __syncthreads();
    for (int off = 1; off < 512; off <<= 1) {
        unsigned u = (t >= off) ? sh[t - off] : 0u;
        __syncthreads();
        sh[t] += u;
        __syncthreads();
    }
    if (t < NBKT) {
        unsigned ex = t ? sh[t - 1] : 0u;
        bkt_base[t] = ex;
        bkt_cur[t] = ex;
    }
}

// bin edges into bucket-contiguous runs: packed word = (src<<8)|dst_local
__global__ __launch_bounds__(256) void k_bin(const int* __restrict__ src,
                                             const int* __restrict__ dst,
                                             unsigned* __restrict__ bkt_cur,
                                             unsigned* __restrict__ binned) {
    __shared__ unsigned lh[NBKT];
    int t = threadIdx.x;
    unsigned b0 = blockIdx.x * CHUNK;
    unsigned b1 = min(b0 + CHUNK, (unsigned)NE);
    for (int b = t; b < NBKT; b += 256) lh[b] = 0u;
    __syncthreads();
    for (unsigned i = b0 + t; i < b1; i += 256)
        atomicAdd(&lh[((unsigned)dst[i]) >> BSH], 1u);
    __syncthreads();
    for (int b = t; b < NBKT; b += 256) {
        unsigned c = lh[b];
        lh[b] = c ? atomicAdd(&bkt_cur[b], c) : 0u;   // global run base for this block
    }
    __syncthreads();
    for (unsigned i = b0 + t; i < b1; i += 256) {
        unsigned dv = (unsigned)dst[i];
        unsigned bk = dv >> BSH;
        unsigned pos = atomicAdd(&lh[bk], 1u);
        binned[pos] = (((unsigned)src[i]) << BSH) | (dv & BMASK);
    }
}

// per-bucket counting sort; writes global row offsets + dst-sorted src ids
__global__ __launch_bounds__(256) void k_bsort(const unsigned* __restrict__ bkt_base,
                                               const unsigned* __restrict__ binned,
                                               int* __restrict__ perm,
                                               unsigned* __restrict__ rowp) {
    __shared__ unsigned lh[256];
    __shared__ unsigned cur[256];
    int t = threadIdx.x;
    int b = blockIdx.x;
    unsigned beg = bkt_base[b];
    unsigned end = (b == NBKT - 1) ? (unsigned)NE : bkt_base[b + 1];
    lh[t] = 0u;
    __syncthreads();
    for (unsigned i = beg + t; i < end; i += 256)
        atomicAdd(&lh[binned[i] & BMASK], 1u);
    __syncthreads();
    for (int off = 1; off < 256; off <<= 1) {      // inclusive scan of lh
        unsigned u = (t >= off) ? lh[t - off] : 0u;
        __syncthreads();
        lh[t] += u;
        __syncthreads();
    }
    unsigned start = (t == 0) ? 0u : lh[t - 1];
    unsigned node = ((unsigned)b << BSH) + (unsigned)t;
    if (node <= NN) rowp[node] = beg + start;      // row[NN]=NE from last bucket
    cur[t] = start;
    __syncthreads();
    for (unsigned i = beg + t; i < end; i += 256) {
        unsigned w = binned[i];                     // L2-hot second read
        unsigned pos = atomicAdd(&cur[w & BMASK], 1u);
        perm[beg + pos] = (int)(w >> BSH);
    }
}

// ---------------- dense phase ----------------

// ft = feat @ W. W column `lane` lives in 64 VGPRs; feat row arrives via
// wave-uniform (scalar) loads; zero LDS/DS ops in the k-loop.
__global__ __launch_bounds__(256) void k1_fc(const float* __restrict__ feat,
                                             const float* __restrict__ W,
                                             const float* __restrict__ attn_l,
                                             const float* __restrict__ attn_r,
                                             float* __restrict__ ft,
                                             float* __restrict__ el,
                                             float* __restrict__ er) {
    int lane = threadIdx.x & 63;
    int wv = __builtin_amdgcn_readfirstlane(threadIdx.x >> 6);

    float wreg[64];
    #pragma unroll
    for (int k = 0; k < 64; ++k) wreg[k] = W[k * D + lane];
    float al = attn_l[lane];
    float ar = attn_r[lane];

    int n0 = blockIdx.x * 64 + wv * 16;
    #pragma unroll 1
    for (int r = 0; r < 16; ++r) {
        int n = n0 + r;
        if (n >= NN) return;
        const float* p = feat + (size_t)n * D;   // wave-uniform address
        float a0 = 0.f, a1 = 0.f, a2 = 0.f, a3 = 0.f;
        #pragma unroll
        for (int kk = 0; kk < 4; ++kk) {
            float f[16];
            #pragma unroll
            for (int k = 0; k < 16; ++k) f[k] = p[kk * 16 + k];
            #pragma unroll
            for (int k = 0; k < 16; ++k) {
                int ki = kk * 16 + k;
                if ((k & 3) == 0)      a0 = fmaf(f[k], wreg[ki], a0);
                else if ((k & 3) == 1) a1 = fmaf(f[k], wreg[ki], a1);
                else if ((k & 3) == 2) a2 = fmaf(f[k], wreg[ki], a2);
                else                   a3 = fmaf(f[k], wreg[ki], a3);
            }
        }
        float a = (a0 + a1) + (a2 + a3);
        ft[(size_t)n * D + lane] = a;
        float pl = wave_sum63(a * al);
        float pr = wave_sum63(a * ar);
        if (lane == 63) { el[n] = pl; er[n] = pr; }
    }
}

// fused edge-softmax + weighted aggregation + residual + bias
// one wave per destination node; 8 gather loads kept in flight
__global__ __launch_bounds__(256) void k_agg(const unsigned* __restrict__ row,
                                             const int* __restrict__ perm_src,
                                             const float* __restrict__ el,
                                             const float* __restrict__ er,
                                             const float* __restrict__ ft,
                                             const float* __restrict__ feat,
                                             const float* __restrict__ bias,
                                             float* __restrict__ out) {
    int gid = blockIdx.x * 256 + threadIdx.x;
    int d = gid >> 6;
    int lane = gid & 63;
    if (d >= NN) return;

    unsigned beg = row[d], end = row[d + 1];
    int deg = (int)(end - beg);
    float er_d = er[d];
    float acc = 0.0f;
    float s = 0.0f;

    if (deg <= 64) {
        int sid = 0;
        float e = -INFINITY;
        if (lane < deg) {
            sid = perm_src[beg + lane];
            float v = el[sid] + er_d;
            e = v > 0.0f ? v : NEG_SLOPE * v;
        }
        float m = e;
        #pragma unroll
        for (int off = 32; off > 0; off >>= 1) m = fmaxf(m, __shfl_xor(m, off, 64));
        float ex = (lane < deg) ? __expf(e - m) : 0.0f;
        s = ex;
        #pragma unroll
        for (int off = 32; off > 0; off >>= 1) s += __shfl_xor(s, off, 64);
        float inv_s = (deg > 0) ? __frcp_rn(s) : 0.0f;

        // broadcast via readlane (no DS ops); 8 row-gathers in flight
        int j = 0;
        for (; j + 8 <= deg; j += 8) {
            int s0 = __builtin_amdgcn_readlane(sid, j + 0);
            int s1 = __builtin_amdgcn_readlane(sid, j + 1);
            int s2 = __builtin_amdgcn_readlane(sid, j + 2);
            int s3 = __builtin_amdgcn_readlane(sid, j + 3);
            int s4 = __builtin_amdgcn_readlane(sid, j + 4);
            int s5 = __builtin_amdgcn_readlane(sid, j + 5);
            int s6 = __builtin_amdgcn_readlane(sid, j + 6);
            int s7 = __builtin_amdgcn_readlane(sid, j + 7);
            float f0 = ft[(size_t)s0 * D + lane];
            float f1 = ft[(size_t)s1 * D + lane];
            float f2 = ft[(size_t)s2 * D + lane];
            float f3 = ft[(size_t)s3 * D + lane];
            float f4 = ft[(size_t)s4 * D + lane];
            float f5 = ft[(size_t)s5 * D + lane];
            float f6 = ft[(size_t)s6 * D + lane];
            float f7 = ft[(size_t)s7 * D + lane];
            float a0 = rdlane_f(ex, j + 0);
            float a1 = rdlane_f(ex, j + 1);
            float a2 = rdlane_f(ex, j + 2);
            float a3 = rdlane_f(ex, j + 3);
            float a4 = rdlane_f(ex, j + 4);
            float a5 = rdlane_f(ex, j + 5);
            float a6 = rdlane_f(ex, j + 6);
            float a7 = rdlane_f(ex, j + 7);
            acc = fmaf(f0, a0, acc); acc = fmaf(f1, a1, acc);
            acc = fmaf(f2, a2, acc); acc = fmaf(f3, a3, acc);
            acc = fmaf(f4, a4, acc); acc = fmaf(f5, a5, acc);
            acc = fmaf(f6, a6, acc); acc = fmaf(f7, a7, acc);
        }
        for (; j < deg; ++j) {
            int sj = __builtin_amdgcn_readlane(sid, j);
            float aj = rdlane_f(ex, j);
            acc = fmaf(ft[(size_t)sj * D + lane], aj, acc);
        }
        acc *= inv_s;
    } else {
        float m = -INFINITY;
        for (unsigned base = beg; base < end; base += 64) {
            unsigned i = base + lane;
            float e = -INFINITY;
            if (i < end) {
                int sid2 = perm_src[i];
                float v = el[sid2] + er_d;
                e = v > 0.0f ? v : NEG_SLOPE * v;
            }
            #pragma unroll
            for (int off = 32; off > 0; off >>= 1) e = fmaxf(e, __shfl_xor(e, off, 64));
            m = fmaxf(m, e);
        }
        for (unsigned base = beg; base < end; base += 64) {
            unsigned i = base + lane;
            float exx = 0.0f;
            if (i < end) {
                int sid2 = perm_src[i];
                float v = el[sid2] + er_d;
                v = v > 0.0f ? v : NEG_SLOPE * v;
                exx = __expf(v - m);
            }
            #pragma unroll
            for (int off = 32; off > 0; off >>= 1) exx += __shfl_xor(exx, off, 64);
            s += exx;
        }
        for (unsigned jj = beg; jj < end; ++jj) {
            int sj = perm_src[jj];
            float v = el[sj] + er_d;
            v = v > 0.0f ? v : NEG_SLOPE * v;
            acc = fmaf(ft[(size_t)sj * D + lane], __expf(v - m), acc);
        }
        acc /= s;
    }

    out[(size_t)d * D + lane] = acc + feat[(size_t)d * D + lane] + bias[lane];
}

extern "C" void kernel_launch(void* const* d_in, const int* in_sizes, int n_in,
                              void* d_out, int out_size, void* d_ws, size_t ws_size,
                              hipStream_t stream) {
    const float* feat   = (const float*)d_in[0];
    const float* W      = (const float*)d_in[1];
    const float* attn_l = (const float*)d_in[2];
    const float* attn_r = (const float*)d_in[3];
    const float* bias   = (const float*)d_in[4];
    const int*   src    = (const int*)d_in[5];
    const int*   dst    = (const int*)d_in[6];
    float* out = (float*)d_out;

    char* ws = (char*)d_ws;
    float*    ft     = (float*)(ws);                 // 25,600,000 B
    unsigned* binned = (unsigned*)(ws);              // aliases ft[0:6.4MB]; dead before k1_fc
    float*    el     = (float*)(ws + 25600000);      // 400,000 B
    float*    er     = (float*)(ws + 26000000);      // 400,000 B
    int*      perm   = (int*)(ws + 26400000);        // 6,400,000 B
    unsigned* rowp   = (unsigned*)(ws + 32800000);   // 400,004 B  (NN+1)
    unsigned* bcnt   = (unsigned*)(ws + 33200004);   // 1,564 B
    unsigned* bbase  = (unsigned*)(ws + 33201568);   // 1,564 B
    unsigned* bcur   = (unsigned*)(ws + 33203132);   // 1,564 B  (end 33,204,696)

    hipMemsetAsync(bcnt, 0, NBKT * sizeof(unsigned), stream);
    k_bhist<<<NB1, 256, 0, stream>>>(dst, bcnt);
    k_bscan<<<1, 512, 0, stream>>>(bcnt, bbase, bcur);
    k_bin<<<NB1, 256, 0, stream>>>(src, dst, bcur, binned);
    k_bsort<<<NBKT, 256, 0, stream>>>(bbase, binned, perm, rowp);

    k1_fc<<<(NN + 63) / 64, 256, 0, stream>>>(feat, W, attn_l, attn_r, ft, el, er);
    k_agg<<<(NN * 64 + 255) / 256, 256, 0, stream>>>(rowp, perm, el, er,
                                                     ft, feat, bias, out);
}

// Round 6
// 160.739 us; speedup vs baseline: 3.9082x; 1.0840x over previous
//
#include <hip/hip_runtime.h>
#include <hip/hip_fp16.h>
#include <math.h>

#define NN 100000
#define NE 1600000
#define D 64
#define NEG_SLOPE 0.2f
#define BSH 8
#define BMASK 255
#define NBKT 391          // ceil(NN / 256)
#define NB1 196           // streaming blocks for hist/bin
#define CHUNK 8192        // edges per streaming block (CHUNK % 4 == 0)
#define BKT_CAP 8192      // LDS staging cap for k_bsort (mean bucket = 4096)

// ---------------- DPP wave64 reductions (VALU pipe, no LDS) ----------------
template<int CTRL>
__device__ __forceinline__ float dpp_add(float x) {
    int y = __builtin_amdgcn_update_dpp(0, __float_as_int(x), CTRL, 0xf, 0xf, true);
    return x + __int_as_float(y);
}
template<int CTRL>
__device__ __forceinline__ float dpp_max(float x) {
    int xi = __float_as_int(x);
    int y = __builtin_amdgcn_update_dpp(xi, xi, CTRL, 0xf, 0xf, false); // invalid src -> old (=x)
    return fmaxf(x, __int_as_float(y));
}
// full 64-lane sum, valid in lane 63
__device__ __forceinline__ float wave_sum63(float x) {
    x = dpp_add<0x111>(x);   // row_shr:1
    x = dpp_add<0x112>(x);   // row_shr:2
    x = dpp_add<0x114>(x);   // row_shr:4
    x = dpp_add<0x118>(x);   // row_shr:8
    x = dpp_add<0x142>(x);   // row_bcast:15
    x = dpp_add<0x143>(x);   // row_bcast:31
    return x;
}
// full 64-lane max, valid in lane 63
__device__ __forceinline__ float wave_max63(float x) {
    x = dpp_max<0x111>(x);
    x = dpp_max<0x112>(x);
    x = dpp_max<0x114>(x);
    x = dpp_max<0x118>(x);
    x = dpp_max<0x142>(x);
    x = dpp_max<0x143>(x);
    return x;
}
__device__ __forceinline__ float rdlane_f(float v, int l) {
    return __int_as_float(__builtin_amdgcn_readlane(__float_as_int(v), l));
}

// ---------------- bucket histogram (LDS pre-aggregated, int4 stream) --------
__global__ __launch_bounds__(256) void k_bhist(const int* __restrict__ dst,
                                               unsigned* __restrict__ bcnt) {
    __shared__ unsigned lh[NBKT];
    int t = threadIdx.x;
    unsigned b0 = blockIdx.x * CHUNK;
    unsigned b1 = min(b0 + CHUNK, (unsigned)NE);
    for (int b = t; b < NBKT; b += 256) lh[b] = 0u;
    __syncthreads();
    const int4* d4 = (const int4*)(dst + b0);
    unsigned n4 = (b1 - b0) >> 2;
    for (unsigned i = t; i < n4; i += 256) {
        int4 v = d4[i];
        atomicAdd(&lh[((unsigned)v.x) >> BSH], 1u);
        atomicAdd(&lh[((unsigned)v.y) >> BSH], 1u);
        atomicAdd(&lh[((unsigned)v.z) >> BSH], 1u);
        atomicAdd(&lh[((unsigned)v.w) >> BSH], 1u);
    }
    __syncthreads();
    for (int b = t; b < NBKT; b += 256)
        if (lh[b]) atomicAdd(&bcnt[b], lh[b]);
}

// scan 391 bucket counts -> bases + cursors (single block)
__global__ __launch_bounds__(512) void k_bscan(const unsigned* __restrict__ bcnt,
                                               unsigned* __restrict__ bkt_base,
                                               unsigned* __restrict__ bkt_cur) {
    __shared__ unsigned sh[512];
    int t = threadIdx.x;
    sh[t] = (t < NBKT) ? bcnt[t] : 0u;
    __syncthreads();
    for (int off = 1; off < 512; off <<= 1) {
        unsigned u = (t >= off) ? sh[t - off] : 0u;
        __syncthreads();
        sh[t] += u;
        __syncthreads();
    }
    if (t < NBKT) {
        unsigned ex = t ? sh[t - 1] : 0u;
        bkt_base[t] = ex;
        bkt_cur[t] = ex;
    }
}

// bin edges into bucket-contiguous runs: packed word = (src<<8)|dst_local
__global__ __launch_bounds__(256) void k_bin(const int* __restrict__ src,
                                             const int* __restrict__ dst,
                                             unsigned* __restrict__ bkt_cur,
                                             unsigned* __restrict__ binned) {
    __shared__ unsigned lh[NBKT];
    int t = threadIdx.x;
    unsigned b0 = blockIdx.x * CHUNK;
    unsigned b1 = min(b0 + CHUNK, (unsigned)NE);
    for (int b = t; b < NBKT; b += 256) lh[b] = 0u;
    __syncthreads();
    const int4* d4 = (const int4*)(dst + b0);
    const int4* s4 = (const int4*)(src + b0);
    unsigned n4 = (b1 - b0) >> 2;
    for (unsigned i = t; i < n4; i += 256) {
        int4 v = d4[i];
        atomicAdd(&lh[((unsigned)v.x) >> BSH], 1u);
        atomicAdd(&lh[((unsigned)v.y) >> BSH], 1u);
        atomicAdd(&lh[((unsigned)v.z) >> BSH], 1u);
        atomicAdd(&lh[((unsigned)v.w) >> BSH], 1u);
    }
    __syncthreads();
    for (int b = t; b < NBKT; b += 256) {
        unsigned c = lh[b];
        lh[b] = c ? atomicAdd(&bkt_cur[b], c) : 0u;   // global run base for this block
    }
    __syncthreads();
    for (unsigned i = t; i < n4; i += 256) {
        int4 dv = d4[i];
        int4 sv = s4[i];
        {   unsigned d_ = (unsigned)dv.x, s_ = (unsigned)sv.x;
            unsigned pos = atomicAdd(&lh[d_ >> BSH], 1u);
            binned[pos] = (s_ << BSH) | (d_ & BMASK); }
        {   unsigned d_ = (unsigned)dv.y, s_ = (unsigned)sv.y;
            unsigned pos = atomicAdd(&lh[d_ >> BSH], 1u);
            binned[pos] = (s_ << BSH) | (d_ & BMASK); }
        {   unsigned d_ = (unsigned)dv.z, s_ = (unsigned)sv.z;
            unsigned pos = atomicAdd(&lh[d_ >> BSH], 1u);
            binned[pos] = (s_ << BSH) | (d_ & BMASK); }
        {   unsigned d_ = (unsigned)dv.w, s_ = (unsigned)sv.w;
            unsigned pos = atomicAdd(&lh[d_ >> BSH], 1u);
            binned[pos] = (s_ << BSH) | (d_ & BMASK); }
    }
}

// per-bucket counting sort; LDS-staged (fallback to global re-read if huge)
__global__ __launch_bounds__(256) void k_bsort(const unsigned* __restrict__ bkt_base,
                                               const unsigned* __restrict__ binned,
                                               int* __restrict__ perm,
                                               unsigned* __restrict__ rowp) {
    __shared__ unsigned lh[256];
    __shared__ unsigned cur[256];
    __shared__ unsigned stage[BKT_CAP];
    int t = threadIdx.x;
    int b = blockIdx.x;
    unsigned beg = bkt_base[b];
    unsigned end = (b == NBKT - 1) ? (unsigned)NE : bkt_base[b + 1];
    unsigned cnt = end - beg;
    lh[t] = 0u;
    __syncthreads();
    if (cnt <= BKT_CAP) {
        for (unsigned i = t; i < cnt; i += 256) {
            unsigned w = binned[beg + i];
            stage[i] = w;
            atomicAdd(&lh[w & BMASK], 1u);
        }
    } else {
        for (unsigned i = beg + t; i < end; i += 256)
            atomicAdd(&lh[binned[i] & BMASK], 1u);
    }
    __syncthreads();
    for (int off = 1; off < 256; off <<= 1) {      // inclusive scan of lh
        unsigned u = (t >= off) ? lh[t - off] : 0u;
        __syncthreads();
        lh[t] += u;
        __syncthreads();
    }
    unsigned start = (t == 0) ? 0u : lh[t - 1];
    unsigned node = ((unsigned)b << BSH) + (unsigned)t;
    if (node <= NN) rowp[node] = beg + start;      // row[NN]=NE from last bucket
    cur[t] = start;
    __syncthreads();
    if (cnt <= BKT_CAP) {
        for (unsigned i = t; i < cnt; i += 256) {
            unsigned w = stage[i];
            unsigned pos = atomicAdd(&cur[w & BMASK], 1u);
            perm[beg + pos] = (int)(w >> BSH);
        }
    } else {
        for (unsigned i = beg + t; i < end; i += 256) {
            unsigned w = binned[i];
            unsigned pos = atomicAdd(&cur[w & BMASK], 1u);
            perm[beg + pos] = (int)(w >> BSH);
        }
    }
}

// ---------------- dense phase ----------------

// ft = feat @ W (fp16 out). W column `lane` in 64 VGPRs; feat row via
// wave-uniform loads; el/er via DPP reduce.
__global__ __launch_bounds__(256) void k1_fc(const float* __restrict__ feat,
                                             const float* __restrict__ W,
                                             const float* __restrict__ attn_l,
                                             const float* __restrict__ attn_r,
                                             __half* __restrict__ ft,
                                             float* __restrict__ el,
                                             float* __restrict__ er) {
    int lane = threadIdx.x & 63;
    int wv = __builtin_amdgcn_readfirstlane(threadIdx.x >> 6);

    float wreg[64];
    #pragma unroll
    for (int k = 0; k < 64; ++k) wreg[k] = W[k * D + lane];
    float al = attn_l[lane];
    float ar = attn_r[lane];

    int n0 = blockIdx.x * 64 + wv * 16;
    #pragma unroll 1
    for (int r = 0; r < 16; ++r) {
        int n = n0 + r;
        if (n >= NN) return;
        const float* p = feat + (size_t)n * D;   // wave-uniform address
        float a0 = 0.f, a1 = 0.f, a2 = 0.f, a3 = 0.f;
        #pragma unroll
        for (int kk = 0; kk < 4; ++kk) {
            float f[16];
            #pragma unroll
            for (int k = 0; k < 16; ++k) f[k] = p[kk * 16 + k];
            #pragma unroll
            for (int k = 0; k < 16; ++k) {
                int ki = kk * 16 + k;
                if ((k & 3) == 0)      a0 = fmaf(f[k], wreg[ki], a0);
                else if ((k & 3) == 1) a1 = fmaf(f[k], wreg[ki], a1);
                else if ((k & 3) == 2) a2 = fmaf(f[k], wreg[ki], a2);
                else                   a3 = fmaf(f[k], wreg[ki], a3);
            }
        }
        float a = (a0 + a1) + (a2 + a3);
        ft[(size_t)n * D + lane] = __float2half(a);
        float pl = wave_sum63(a * al);
        float pr = wave_sum63(a * ar);
        if (lane == 63) { el[n] = pl; er[n] = pr; }
    }
}

// fused edge-softmax + weighted aggregation + residual + bias
// one wave per destination node; DPP softmax; 8 fp16 row-gathers in flight
__global__ __launch_bounds__(256) void k_agg(const unsigned* __restrict__ row,
                                             const int* __restrict__ perm_src,
                                             const float* __restrict__ el,
                                             const float* __restrict__ er,
                                             const __half* __restrict__ ft,
                                             const float* __restrict__ feat,
                                             const float* __restrict__ bias,
                                             float* __restrict__ out) {
    int gid = blockIdx.x * 256 + threadIdx.x;
    int d = gid >> 6;
    int lane = gid & 63;
    if (d >= NN) return;

    unsigned beg = row[d], end = row[d + 1];
    int deg = (int)(end - beg);
    float er_d = er[d];
    float acc = 0.0f;

    if (deg <= 64) {
        int sid = 0;
        float e = -INFINITY;
        if (lane < deg) {
            sid = perm_src[beg + lane];
            float v = el[sid] + er_d;
            e = v > 0.0f ? v : NEG_SLOPE * v;
        }
        float m = rdlane_f(wave_max63(e), 63);
        float ex = (lane < deg) ? __expf(e - m) : 0.0f;
        float s = rdlane_f(wave_sum63(ex), 63);
        float inv_s = (deg > 0) ? __frcp_rn(s) : 0.0f;

        int j = 0;
        for (; j + 8 <= deg; j += 8) {
            int s0 = __builtin_amdgcn_readlane(sid, j + 0);
            int s1 = __builtin_amdgcn_readlane(sid, j + 1);
            int s2 = __builtin_amdgcn_readlane(sid, j + 2);
            int s3 = __builtin_amdgcn_readlane(sid, j + 3);
            int s4 = __builtin_amdgcn_readlane(sid, j + 4);
            int s5 = __builtin_amdgcn_readlane(sid, j + 5);
            int s6 = __builtin_amdgcn_readlane(sid, j + 6);
            int s7 = __builtin_amdgcn_readlane(sid, j + 7);
            float f0 = __half2float(ft[((size_t)s0 << 6) + lane]);
            float f1 = __half2float(ft[((size_t)s1 << 6) + lane]);
            float f2 = __half2float(ft[((size_t)s2 << 6) + lane]);
            float f3 = __half2float(ft[((size_t)s3 << 6) + lane]);
            float f4 = __half2float(ft[((size_t)s4 << 6) + lane]);
            float f5 = __half2float(ft[((size_t)s5 << 6) + lane]);
            float f6 = __half2float(ft[((size_t)s6 << 6) + lane]);
            float f7 = __half2float(ft[((size_t)s7 << 6) + lane]);
            float a0 = rdlane_f(ex, j + 0);
            float a1 = rdlane_f(ex, j + 1);
            float a2 = rdlane_f(ex, j + 2);
            float a3 = rdlane_f(ex, j + 3);
            float a4 = rdlane_f(ex, j + 4);
            float a5 = rdlane_f(ex, j + 5);
            float a6 = rdlane_f(ex, j + 6);
            float a7 = rdlane_f(ex, j + 7);
            acc = fmaf(f0, a0, acc); acc = fmaf(f1, a1, acc);
            acc = fmaf(f2, a2, acc); acc = fmaf(f3, a3, acc);
            acc = fmaf(f4, a4, acc); acc = fmaf(f5, a5, acc);
            acc = fmaf(f6, a6, acc); acc = fmaf(f7, a7, acc);
        }
        for (; j < deg; ++j) {
            int sj = __builtin_amdgcn_readlane(sid, j);
            float aj = rdlane_f(ex, j);
            acc = fmaf(__half2float(ft[((size_t)sj << 6) + lane]), aj, acc);
        }
        acc *= inv_s;
    } else {
        float s = 0.0f;
        float m = -INFINITY;
        for (unsigned base = beg; base < end; base += 64) {
            unsigned i = base + lane;
            float e = -INFINITY;
            if (i < end) {
                int sid2 = perm_src[i];
                float v = el[sid2] + er_d;
                e = v > 0.0f ? v : NEG_SLOPE * v;
            }
            m = fmaxf(m, rdlane_f(wave_max63(e), 63));
        }
        for (unsigned base = beg; base < end; base += 64) {
            unsigned i = base + lane;
            float exx = 0.0f;
            if (i < end) {
                int sid2 = perm_src[i];
                float v = el[sid2] + er_d;
                v = v > 0.0f ? v : NEG_SLOPE * v;
                exx = __expf(v - m);
            }
            s += rdlane_f(wave_sum63(exx), 63);
        }
        for (unsigned jj = beg; jj < end; ++jj) {
            int sj = perm_src[jj];
            float v = el[sj] + er_d;
            v = v > 0.0f ? v : NEG_SLOPE * v;
            acc = fmaf(__half2float(ft[((size_t)sj << 6) + lane]), __expf(v - m), acc);
        }
        acc /= s;
    }

    out[(size_t)d * D + lane] = acc + feat[(size_t)d * D + lane] + bias[lane];
}

extern "C" void kernel_launch(void* const* d_in, const int* in_sizes, int n_in,
                              void* d_out, int out_size, void* d_ws, size_t ws_size,
                              hipStream_t stream) {
    const float* feat   = (const float*)d_in[0];
    const float* W      = (const float*)d_in[1];
    const float* attn_l = (const float*)d_in[2];
    const float* attn_r = (const float*)d_in[3];
    const float* bias   = (const float*)d_in[4];
    const int*   src    = (const int*)d_in[5];
    const int*   dst    = (const int*)d_in[6];
    float* out = (float*)d_out;

    char* ws = (char*)d_ws;
    __half*   ft     = (__half*)(ws);                // 12,800,000 B used (slot 25.6MB)
    unsigned* binned = (unsigned*)(ws);              // aliases ft slot; dead before k1_fc
    float*    el     = (float*)(ws + 25600000);      // 400,000 B
    float*    er     = (float*)(ws + 26000000);      // 400,000 B
    int*      perm   = (int*)(ws + 26400000);        // 6,400,000 B
    unsigned* rowp   = (unsigned*)(ws + 32800000);   // 400,004 B  (NN+1)
    unsigned* bcnt   = (unsigned*)(ws + 33200004);   // 1,564 B
    unsigned* bbase  = (unsigned*)(ws + 33201568);   // 1,564 B
    unsigned* bcur   = (unsigned*)(ws + 33203132);   // 1,564 B  (end 33,204,696)

    hipMemsetAsync(bcnt, 0, NBKT * sizeof(unsigned), stream);
    k_bhist<<<NB1, 256, 0, stream>>>(dst, bcnt);
    k_bscan<<<1, 512, 0, stream>>>(bcnt, bbase, bcur);
    k_bin<<<NB1, 256, 0, stream>>>(src, dst, bcur, binned);
    k_bsort<<<NBKT, 256, 0, stream>>>(bbase, binned, perm, rowp);

    k1_fc<<<(NN + 63) / 64, 256, 0, stream>>>(feat, W, attn_l, attn_r, ft, el, er);
    k_agg<<<(NN * 64 + 255) / 256, 256, 0, stream>>>(rowp, perm, el, er,
                                                     ft, feat, bias, out);
}

// Round 7
// 127.079 us; speedup vs baseline: 4.9433x; 1.2649x over previous
//
#include <hip/hip_runtime.h>
#include <hip/hip_fp16.h>
#include <math.h>

#define NN 100000
#define NE 1600000
#define D 64
#define NEG_SLOPE 0.2f
#define BSH 8
#define BMASK 255
#define NBKT 391          // ceil(NN / 256)
#define NB1 196           // streaming blocks for hist/bin
#define CHUNK 8192        // edges per streaming block (CHUNK % 4 == 0)
#define BKT_CAP 8192      // LDS staging cap for k_bsort (mean bucket = 4096)

typedef __attribute__((ext_vector_type(8))) short short8;
typedef __attribute__((ext_vector_type(4))) float f32x4;

// ---------------- DPP wave64 reductions (VALU pipe, no LDS) ----------------
template<int CTRL>
__device__ __forceinline__ float dpp_add(float x) {
    int y = __builtin_amdgcn_update_dpp(0, __float_as_int(x), CTRL, 0xf, 0xf, true);
    return x + __int_as_float(y);
}
template<int CTRL>
__device__ __forceinline__ float dpp_max(float x) {
    int xi = __float_as_int(x);
    int y = __builtin_amdgcn_update_dpp(xi, xi, CTRL, 0xf, 0xf, false);
    return fmaxf(x, __int_as_float(y));
}
__device__ __forceinline__ float wave_sum63(float x) {
    x = dpp_add<0x111>(x); x = dpp_add<0x112>(x); x = dpp_add<0x114>(x);
    x = dpp_add<0x118>(x); x = dpp_add<0x142>(x); x = dpp_add<0x143>(x);
    return x;
}
__device__ __forceinline__ float wave_max63(float x) {
    x = dpp_max<0x111>(x); x = dpp_max<0x112>(x); x = dpp_max<0x114>(x);
    x = dpp_max<0x118>(x); x = dpp_max<0x142>(x); x = dpp_max<0x143>(x);
    return x;
}
__device__ __forceinline__ float rdlane_f(float v, int l) {
    return __int_as_float(__builtin_amdgcn_readlane(__float_as_int(v), l));
}
// RNE float->bf16 bits
__device__ __forceinline__ unsigned bf16_1(float f) {
    unsigned x = __float_as_uint(f);
    return (x + 0x7fffu + ((x >> 16) & 1u)) >> 16;
}
__device__ __forceinline__ unsigned bfpack(float a, float b) {
    return bf16_1(a) | (bf16_1(b) << 16);
}

// ---------------- bucket histogram (LDS pre-aggregated, int4 stream) --------
__global__ __launch_bounds__(256) void k_bhist(const int* __restrict__ dst,
                                               unsigned* __restrict__ bcnt) {
    __shared__ unsigned lh[NBKT];
    int t = threadIdx.x;
    unsigned b0 = blockIdx.x * CHUNK;
    unsigned b1 = min(b0 + CHUNK, (unsigned)NE);
    for (int b = t; b < NBKT; b += 256) lh[b] = 0u;
    __syncthreads();
    const int4* d4 = (const int4*)(dst + b0);
    unsigned n4 = (b1 - b0) >> 2;
    for (unsigned i = t; i < n4; i += 256) {
        int4 v = d4[i];
        atomicAdd(&lh[((unsigned)v.x) >> BSH], 1u);
        atomicAdd(&lh[((unsigned)v.y) >> BSH], 1u);
        atomicAdd(&lh[((unsigned)v.z) >> BSH], 1u);
        atomicAdd(&lh[((unsigned)v.w) >> BSH], 1u);
    }
    __syncthreads();
    for (int b = t; b < NBKT; b += 256)
        if (lh[b]) atomicAdd(&bcnt[b], lh[b]);
}

__global__ __launch_bounds__(512) void k_bscan(const unsigned* __restrict__ bcnt,
                                               unsigned* __restrict__ bkt_base,
                                               unsigned* __restrict__ bkt_cur) {
    __shared__ unsigned sh[512];
    int t = threadIdx.x;
    sh[t] = (t < NBKT) ? bcnt[t] : 0u;
    __syncthreads();
    for (int off = 1; off < 512; off <<= 1) {
        unsigned u = (t >= off) ? sh[t - off] : 0u;
        __syncthreads();
        sh[t] += u;
        __syncthreads();
    }
    if (t < NBKT) {
        unsigned ex = t ? sh[t - 1] : 0u;
        bkt_base[t] = ex;
        bkt_cur[t] = ex;
    }
}

__global__ __launch_bounds__(256) void k_bin(const int* __restrict__ src,
                                             const int* __restrict__ dst,
                                             unsigned* __restrict__ bkt_cur,
                                             unsigned* __restrict__ binned) {
    __shared__ unsigned lh[NBKT];
    int t = threadIdx.x;
    unsigned b0 = blockIdx.x * CHUNK;
    unsigned b1 = min(b0 + CHUNK, (unsigned)NE);
    for (int b = t; b < NBKT; b += 256) lh[b] = 0u;
    __syncthreads();
    const int4* d4 = (const int4*)(dst + b0);
    const int4* s4 = (const int4*)(src + b0);
    unsigned n4 = (b1 - b0) >> 2;
    for (unsigned i = t; i < n4; i += 256) {
        int4 v = d4[i];
        atomicAdd(&lh[((unsigned)v.x) >> BSH], 1u);
        atomicAdd(&lh[((unsigned)v.y) >> BSH], 1u);
        atomicAdd(&lh[((unsigned)v.z) >> BSH], 1u);
        atomicAdd(&lh[((unsigned)v.w) >> BSH], 1u);
    }
    __syncthreads();
    for (int b = t; b < NBKT; b += 256) {
        unsigned c = lh[b];
        lh[b] = c ? atomicAdd(&bkt_cur[b], c) : 0u;
    }
    __syncthreads();
    for (unsigned i = t; i < n4; i += 256) {
        int4 dv = d4[i];
        int4 sv = s4[i];
        {   unsigned d_ = (unsigned)dv.x, s_ = (unsigned)sv.x;
            unsigned pos = atomicAdd(&lh[d_ >> BSH], 1u);
            binned[pos] = (s_ << BSH) | (d_ & BMASK); }
        {   unsigned d_ = (unsigned)dv.y, s_ = (unsigned)sv.y;
            unsigned pos = atomicAdd(&lh[d_ >> BSH], 1u);
            binned[pos] = (s_ << BSH) | (d_ & BMASK); }
        {   unsigned d_ = (unsigned)dv.z, s_ = (unsigned)sv.z;
            unsigned pos = atomicAdd(&lh[d_ >> BSH], 1u);
            binned[pos] = (s_ << BSH) | (d_ & BMASK); }
        {   unsigned d_ = (unsigned)dv.w, s_ = (unsigned)sv.w;
            unsigned pos = atomicAdd(&lh[d_ >> BSH], 1u);
            binned[pos] = (s_ << BSH) | (d_ & BMASK); }
    }
}

__global__ __launch_bounds__(256) void k_bsort(const unsigned* __restrict__ bkt_base,
                                               const unsigned* __restrict__ binned,
                                               int* __restrict__ perm,
                                               unsigned* __restrict__ rowp) {
    __shared__ unsigned lh[256];
    __shared__ unsigned cur[256];
    __shared__ unsigned stage[BKT_CAP];
    int t = threadIdx.x;
    int b = blockIdx.x;
    unsigned beg = bkt_base[b];
    unsigned end = (b == NBKT - 1) ? (unsigned)NE : bkt_base[b + 1];
    unsigned cnt = end - beg;
    lh[t] = 0u;
    __syncthreads();
    if (cnt <= BKT_CAP) {
        for (unsigned i = t; i < cnt; i += 256) {
            unsigned w = binned[beg + i];
            stage[i] = w;
            atomicAdd(&lh[w & BMASK], 1u);
        }
    } else {
        for (unsigned i = beg + t; i < end; i += 256)
            atomicAdd(&lh[binned[i] & BMASK], 1u);
    }
    __syncthreads();
    for (int off = 1; off < 256; off <<= 1) {
        unsigned u = (t >= off) ? lh[t - off] : 0u;
        __syncthreads();
        lh[t] += u;
        __syncthreads();
    }
    unsigned start = (t == 0) ? 0u : lh[t - 1];
    unsigned node = ((unsigned)b << BSH) + (unsigned)t;
    if (node <= NN) rowp[node] = beg + start;
    cur[t] = start;
    __syncthreads();
    if (cnt <= BKT_CAP) {
        for (unsigned i = t; i < cnt; i += 256) {
            unsigned w = stage[i];
            unsigned pos = atomicAdd(&cur[w & BMASK], 1u);
            perm[beg + pos] = (int)(w >> BSH);
        }
    } else {
        for (unsigned i = beg + t; i < end; i += 256) {
            unsigned w = binned[i];
            unsigned pos = atomicAdd(&cur[w & BMASK], 1u);
            perm[beg + pos] = (int)(w >> BSH);
        }
    }
}

// ---------------- dense phase ----------------

// prep: wl = W@attn_l, wr = W@attn_r (fp32); Wt_bf16[j][k] = bf16(W[k][j])
__global__ __launch_bounds__(256) void k_wprep(const float* __restrict__ W,
                                               const float* __restrict__ attn_l,
                                               const float* __restrict__ attn_r,
                                               float* __restrict__ wl,
                                               float* __restrict__ wr,
                                               unsigned short* __restrict__ Wtb) {
    int t = threadIdx.x;
    {   // wl/wr: thread (k = t>>2, s = t&3)
        int k = t >> 2, s = t & 3;
        float pl = 0.f, pr = 0.f;
        #pragma unroll
        for (int q = 0; q < 4; ++q) {
            int seg = s + q * 4;
            float4 f = *(const float4*)(W + k * 64 + seg * 4);
            float4 a = *(const float4*)(attn_l + seg * 4);
            float4 b = *(const float4*)(attn_r + seg * 4);
            pl += f.x * a.x + f.y * a.y + f.z * a.z + f.w * a.w;
            pr += f.x * b.x + f.y * b.y + f.z * b.z + f.w * b.w;
        }
        pl += __shfl_xor(pl, 1, 64); pl += __shfl_xor(pl, 2, 64);
        pr += __shfl_xor(pr, 1, 64); pr += __shfl_xor(pr, 2, 64);
        if (s == 0) { wl[k] = pl; wr[k] = pr; }
    }
    {   // W^T bf16: thread (j = t&63, g = t>>6)
        int j = t & 63, g = t >> 6;
        #pragma unroll
        for (int i = 0; i < 8; ++i) {
            int k0 = g * 16 + i * 2;
            float w0 = W[k0 * 64 + j];
            float w1 = W[(k0 + 1) * 64 + j];
            *(unsigned*)(Wtb + j * 64 + k0) = bfpack(w0, w1);
        }
    }
}

// MFMA GEMM: block = 64 nodes. feat fp32 -> bf16 LDS (XOR-swizzled),
// W^T bf16 LDS; 8x mfma_f32_16x16x32_bf16 per wave; ft out fp16.
// el/er computed exactly in fp32 during staging (feat . wl / wr).
__global__ __launch_bounds__(256) void k1_mfma(const float* __restrict__ feat,
                                               const float* __restrict__ wl,
                                               const float* __restrict__ wr,
                                               const unsigned short* __restrict__ Wtb,
                                               __half* __restrict__ ft,
                                               float* __restrict__ el,
                                               float* __restrict__ er) {
    __shared__ unsigned short Ab[64 * 64];   // 8KB, swizzled rows
    __shared__ unsigned short Bb[64 * 64];   // 8KB, swizzled rows
    int t = threadIdx.x;
    int n0 = blockIdx.x * 64;

    // stage W^T (bf16) -> Bb
    {
        int j = t >> 2, q = t & 3;
        uint4 w0 = *(const uint4*)(Wtb + j * 64 + q * 16);
        uint4 w1 = *(const uint4*)(Wtb + j * 64 + q * 16 + 8);
        unsigned m = (unsigned)((j & 7) << 4);
        *(uint4*)((char*)Bb + j * 128 + (((unsigned)(q * 32)) ^ m)) = w0;
        *(uint4*)((char*)Bb + j * 128 + (((unsigned)(q * 32 + 16)) ^ m)) = w1;
    }
    // stage feat tile -> Ab (bf16) + exact fp32 el/er
    {
        int r = t >> 2, s = t & 3;
        int n = n0 + r;
        bool valid = n < NN;
        const float* fp = feat + (size_t)(valid ? n : (NN - 1)) * D;
        float pl = 0.f, pr = 0.f;
        unsigned m = (unsigned)((r & 7) << 4);
        #pragma unroll
        for (int q = 0; q < 4; ++q) {
            int seg = s + q * 4;                       // float4 index 0..15
            float4 f = *(const float4*)(fp + seg * 4);
            float4 a = *(const float4*)(wl + seg * 4);
            float4 b = *(const float4*)(wr + seg * 4);
            pl += f.x * a.x + f.y * a.y + f.z * a.z + f.w * a.w;
            pr += f.x * b.x + f.y * b.y + f.z * b.z + f.w * b.w;
            uint2 pk;
            pk.x = bfpack(f.x, f.y);
            pk.y = bfpack(f.z, f.w);
            *(uint2*)((char*)Ab + r * 128 + (((unsigned)(seg * 8)) ^ m)) = pk;
        }
        pl += __shfl_xor(pl, 1, 64); pl += __shfl_xor(pl, 2, 64);
        pr += __shfl_xor(pr, 1, 64); pr += __shfl_xor(pr, 2, 64);
        if (s == 0 && valid) { el[n] = pl; er[n] = pr; }
    }
    __syncthreads();

    // MFMA: wave w -> out cols 16w..16w+15, rows 0..63
    int w = t >> 6, l = t & 63;
    int lr = l & 15, lg = l >> 4;
    f32x4 acc0 = {0.f, 0.f, 0.f, 0.f};
    f32x4 acc1 = {0.f, 0.f, 0.f, 0.f};
    f32x4 acc2 = {0.f, 0.f, 0.f, 0.f};
    f32x4 acc3 = {0.f, 0.f, 0.f, 0.f};

    int jrow = w * 16 + lr;
    unsigned bm = (unsigned)((jrow & 7) << 4);
    short8 bf0 = *(const short8*)((char*)Bb + jrow * 128 + (((unsigned)(0 + lg * 16)) ^ bm));
    short8 bf1 = *(const short8*)((char*)Bb + jrow * 128 + (((unsigned)(64 + lg * 16)) ^ bm));

    #pragma unroll
    for (int rt = 0; rt < 4; ++rt) {
        int arow = rt * 16 + lr;
        unsigned am = (unsigned)((arow & 7) << 4);
        short8 a0 = *(const short8*)((char*)Ab + arow * 128 + (((unsigned)(0 + lg * 16)) ^ am));
        short8 a1 = *(const short8*)((char*)Ab + arow * 128 + (((unsigned)(64 + lg * 16)) ^ am));
        f32x4 acc = (rt == 0) ? acc0 : (rt == 1) ? acc1 : (rt == 2) ? acc2 : acc3;
        acc = __builtin_amdgcn_mfma_f32_16x16x32_bf16(a0, bf0, acc, 0, 0, 0);
        acc = __builtin_amdgcn_mfma_f32_16x16x32_bf16(a1, bf1, acc, 0, 0, 0);
        if (rt == 0) acc0 = acc; else if (rt == 1) acc1 = acc;
        else if (rt == 2) acc2 = acc; else acc3 = acc;
    }

    // store ft fp16: C layout col=lane&15, row=(lane>>4)*4+reg
    int col = w * 16 + lr;
    #pragma unroll
    for (int rt = 0; rt < 4; ++rt) {
        f32x4 acc = (rt == 0) ? acc0 : (rt == 1) ? acc1 : (rt == 2) ? acc2 : acc3;
        #pragma unroll
        for (int i = 0; i < 4; ++i) {
            int row = rt * 16 + lg * 4 + i;
            int nn = n0 + row;
            if (nn < NN) ft[(size_t)nn * D + col] = __float2half(acc[i]);
        }
    }
}

// fused edge-softmax + weighted aggregation + residual + bias
__global__ __launch_bounds__(256) void k_agg(const unsigned* __restrict__ row,
                                             const int* __restrict__ perm_src,
                                             const float* __restrict__ el,
                                             const float* __restrict__ er,
                                             const __half* __restrict__ ft,
                                             const float* __restrict__ feat,
                                             const float* __restrict__ bias,
                                             float* __restrict__ out) {
    int gid = blockIdx.x * 256 + threadIdx.x;
    int d = gid >> 6;
    int lane = gid & 63;
    if (d >= NN) return;

    unsigned beg = row[d], end = row[d + 1];
    int deg = (int)(end - beg);
    float er_d = er[d];
    float acc = 0.0f;

    if (deg <= 64) {
        int sid = 0;
        float e = -INFINITY;
        if (lane < deg) {
            sid = perm_src[beg + lane];
            float v = el[sid] + er_d;
            e = v > 0.0f ? v : NEG_SLOPE * v;
        }
        float m = rdlane_f(wave_max63(e), 63);
        float ex = (lane < deg) ? __expf(e - m) : 0.0f;
        float s = rdlane_f(wave_sum63(ex), 63);
        float inv_s = (deg > 0) ? __frcp_rn(s) : 0.0f;

        int j = 0;
        for (; j + 8 <= deg; j += 8) {
            int s0 = __builtin_amdgcn_readlane(sid, j + 0);
            int s1 = __builtin_amdgcn_readlane(sid, j + 1);
            int s2 = __builtin_amdgcn_readlane(sid, j + 2);
            int s3 = __builtin_amdgcn_readlane(sid, j + 3);
            int s4 = __builtin_amdgcn_readlane(sid, j + 4);
            int s5 = __builtin_amdgcn_readlane(sid, j + 5);
            int s6 = __builtin_amdgcn_readlane(sid, j + 6);
            int s7 = __builtin_amdgcn_readlane(sid, j + 7);
            float f0 = __half2float(ft[((size_t)s0 << 6) + lane]);
            float f1 = __half2float(ft[((size_t)s1 << 6) + lane]);
            float f2 = __half2float(ft[((size_t)s2 << 6) + lane]);
            float f3 = __half2float(ft[((size_t)s3 << 6) + lane]);
            float f4 = __half2float(ft[((size_t)s4 << 6) + lane]);
            float f5 = __half2float(ft[((size_t)s5 << 6) + lane]);
            float f6 = __half2float(ft[((size_t)s6 << 6) + lane]);
            float f7 = __half2float(ft[((size_t)s7 << 6) + lane]);
            float a0 = rdlane_f(ex, j + 0);
            float a1 = rdlane_f(ex, j + 1);
            float a2 = rdlane_f(ex, j + 2);
            float a3 = rdlane_f(ex, j + 3);
            float a4 = rdlane_f(ex, j + 4);
            float a5 = rdlane_f(ex, j + 5);
            float a6 = rdlane_f(ex, j + 6);
            float a7 = rdlane_f(ex, j + 7);
            acc = fmaf(f0, a0, acc); acc = fmaf(f1, a1, acc);
            acc = fmaf(f2, a2, acc); acc = fmaf(f3, a3, acc);
            acc = fmaf(f4, a4, acc); acc = fmaf(f5, a5, acc);
            acc = fmaf(f6, a6, acc); acc = fmaf(f7, a7, acc);
        }
        for (; j < deg; ++j) {
            int sj = __builtin_amdgcn_readlane(sid, j);
            float aj = rdlane_f(ex, j);
            acc = fmaf(__half2float(ft[((size_t)sj << 6) + lane]), aj, acc);
        }
        acc *= inv_s;
    } else {
        float s = 0.0f;
        float m = -INFINITY;
        for (unsigned base = beg; base < end; base += 64) {
            unsigned i = base + lane;
            float e = -INFINITY;
            if (i < end) {
                int sid2 = perm_src[i];
                float v = el[sid2] + er_d;
                e = v > 0.0f ? v : NEG_SLOPE * v;
            }
            m = fmaxf(m, rdlane_f(wave_max63(e), 63));
        }
        for (unsigned base = beg; base < end; base += 64) {
            unsigned i = base + lane;
            float exx = 0.0f;
            if (i < end) {
                int sid2 = perm_src[i];
                float v = el[sid2] + er_d;
                v = v > 0.0f ? v : NEG_SLOPE * v;
                exx = __expf(v - m);
            }
            s += rdlane_f(wave_sum63(exx), 63);
        }
        for (unsigned jj = beg; jj < end; ++jj) {
            int sj = perm_src[jj];
            float v = el[sj] + er_d;
            v = v > 0.0f ? v : NEG_SLOPE * v;
            acc = fmaf(__half2float(ft[((size_t)sj << 6) + lane]), __expf(v - m), acc);
        }
        acc /= s;
    }

    out[(size_t)d * D + lane] = acc + feat[(size_t)d * D + lane] + bias[lane];
}

extern "C" void kernel_launch(void* const* d_in, const int* in_sizes, int n_in,
                              void* d_out, int out_size, void* d_ws, size_t ws_size,
                              hipStream_t stream) {
    const float* feat   = (const float*)d_in[0];
    const float* W      = (const float*)d_in[1];
    const float* attn_l = (const float*)d_in[2];
    const float* attn_r = (const float*)d_in[3];
    const float* bias   = (const float*)d_in[4];
    const int*   src    = (const int*)d_in[5];
    const int*   dst    = (const int*)d_in[6];
    float* out = (float*)d_out;

    char* ws = (char*)d_ws;
    __half*   ft     = (__half*)(ws);                // [0, 12.8MB)
    unsigned* binned = (unsigned*)(ws);              // aliases [0, 6.4MB); dead before k1
    float*    wl     = (float*)(ws + 12800000);      // 256 B
    float*    wr     = (float*)(ws + 12800256);      // 256 B
    unsigned short* Wtb = (unsigned short*)(ws + 12800512); // 8192 B
    float*    el     = (float*)(ws + 25600000);      // 400,000 B
    float*    er     = (float*)(ws + 26000000);      // 400,000 B
    int*      perm   = (int*)(ws + 26400000);        // 6,400,000 B
    unsigned* rowp   = (unsigned*)(ws + 32800000);   // 400,004 B (NN+1)
    unsigned* bcnt   = (unsigned*)(ws + 33200004);   // 1,564 B
    unsigned* bbase  = (unsigned*)(ws + 33201568);   // 1,564 B
    unsigned* bcur   = (unsigned*)(ws + 33203132);   // 1,564 B

    hipMemsetAsync(bcnt, 0, NBKT * sizeof(unsigned), stream);
    k_wprep<<<1, 256, 0, stream>>>(W, attn_l, attn_r, wl, wr, Wtb);
    k_bhist<<<NB1, 256, 0, stream>>>(dst, bcnt);
    k_bscan<<<1, 512, 0, stream>>>(bcnt, bbase, bcur);
    k_bin<<<NB1, 256, 0, stream>>>(src, dst, bcur, binned);
    k_bsort<<<NBKT, 256, 0, stream>>>(bbase, binned, perm, rowp);

    k1_mfma<<<(NN + 63) / 64, 256, 0, stream>>>(feat, wl, wr, Wtb, ft, el, er);
    k_agg<<<(NN * 64 + 255) / 256, 256, 0, stream>>>(rowp, perm, el, er,
                                                     ft, feat, bias, out);
}